// Round 1
// baseline (170.769 us; speedup 1.0000x reference)
//
#include <hip/hip_runtime.h>
#include <stdint.h>

typedef _Float16 h8v __attribute__((ext_vector_type(8)));
typedef _Float16 h4v __attribute__((ext_vector_type(4)));
typedef float f4v __attribute__((ext_vector_type(4)));
typedef _Float16 f16;

#define NB 8
#define CC 128
#define CB 64
#define NN 4096
#define L2E 1.4426950408889634f

// ---------------------------------------------------------------------------
// Kernel 0: pack weights into f16 MFMA-fragment order (once per launch).
// Wp[((ks*4+kc)*64 + lane)*8 + j] <- W[(ks*16+(lane&15))*CC + kc*32+((lane>>4)&3)*8 + j]
// wth pre-scaled by log2(e) for attn's exp2 softmax.
// ---------------------------------------------------------------------------
__global__ __launch_bounds__(256) void pack_w(
    const float* __restrict__ wth, const float* __restrict__ wph,
    const float* __restrict__ wg,  const float* __restrict__ wl,
    f16* __restrict__ wthp, f16* __restrict__ wphp,
    f16* __restrict__ wgp,  f16* __restrict__ wlp)
{
    const int t = blockIdx.x * 256 + threadIdx.x;      // 2048 threads
    for (int i = t; i < 8192; i += 2048){
        const int j = i & 7, lane = (i >> 3) & 63, kc = (i >> 9) & 3, ks = i >> 11;
        const int row = ks * 16 + (lane & 15);
        const int col = kc * 32 + ((lane >> 4) & 3) * 8 + j;
        wthp[i] = (f16)(wth[row * CC + col] * L2E);
        wphp[i] = (f16)(wph[row * CC + col]);
        wgp [i] = (f16)(wg [row * CC + col]);
    }
    for (int i = t; i < 8192; i += 2048){
        const int j = i & 7, lane = (i >> 3) & 63, kc = (i >> 9) & 1, cs = i >> 10;
        const int row = cs * 16 + (lane & 15);
        const int col = kc * 32 + ((lane >> 4) & 3) * 8 + j;
        wlp[i] = (f16)(wl[row * CB + col]);
    }
}

// ---------------------------------------------------------------------------
// Kernel 1: projections (unchanged this round).
// ---------------------------------------------------------------------------
__global__ __launch_bounds__(256) void proj_kernel(
    const float* __restrict__ x, const f16* __restrict__ wthp,
    const f16* __restrict__ wphp, const f16* __restrict__ wgp,
    f16* __restrict__ thetaT, f16* __restrict__ phiT, f16* __restrict__ gbuf)
{
    __shared__ __align__(16) f16 xT[64][136];
    __shared__ __align__(16) f16 rep[4][16 * 72];
    const int b  = blockIdx.x & 7;
    const int n0 = (blockIdx.x >> 3) << 6;
    const int t  = threadIdx.x;

    #pragma unroll
    for (int i = 0; i < 8; i++){
        int v  = t + 256 * i;
        int c  = v >> 4;
        int j0 = (v & 15) << 2;
        const f4v xv = *(const f4v*)&x[((size_t)(b * CC + c)) * NN + n0 + j0];
        #pragma unroll
        for (int jj = 0; jj < 4; jj++) xT[j0 + jj][c] = (f16)xv[jj];
    }
    __syncthreads();

    const int w = t >> 6, lane = t & 63, quad = lane >> 4, l15 = lane & 15;
    const int rrow = lane >> 3, rcol = (lane & 7) * 8;

    h8v bx[4];
    #pragma unroll
    for (int kc = 0; kc < 4; kc++)
        bx[kc] = *(const h8v*)&xT[w * 16 + l15][kc * 32 + quad * 8];

    #pragma unroll
    for (int m3 = 0; m3 < 2; m3++){
        const f16* WP = (m3 == 0) ? wthp : wphp;
        f16* OUT      = (m3 == 0) ? thetaT : phiT;
        for (int ks = 0; ks < 4; ks++){
            f4v acc = {0.f, 0.f, 0.f, 0.f};
            #pragma unroll
            for (int kc = 0; kc < 4; kc++){
                const h8v af = *(const h8v*)&WP[(ks * 4 + kc) * 512 + lane * 8];
                acc = __builtin_amdgcn_mfma_f32_16x16x32_f16(af, bx[kc], acc, 0, 0, 0);
            }
            h4v pv;
            #pragma unroll
            for (int r = 0; r < 4; r++) pv[r] = (f16)acc[r];
            *(h4v*)&rep[w][l15 * 72 + ks * 16 + quad * 4] = pv;
        }
        #pragma unroll
        for (int j = 0; j < 2; j++){
            const h8v vv = *(const h8v*)&rep[w][(rrow + 8 * j) * 72 + rcol];
            *(h8v*)&OUT[((size_t)(b * NN + n0 + w * 16 + rrow + 8 * j)) * CB + rcol] = vv;
        }
    }

    h8v bw[4];
    #pragma unroll
    for (int kc = 0; kc < 4; kc++)
        bw[kc] = *(const h8v*)&wgp[(w * 4 + kc) * 512 + lane * 8];
    for (int ns = 0; ns < 4; ns++){
        f4v acc = {0.f, 0.f, 0.f, 0.f};
        #pragma unroll
        for (int kc = 0; kc < 4; kc++){
            const h8v af = *(const h8v*)&xT[ns * 16 + l15][kc * 32 + quad * 8];
            acc = __builtin_amdgcn_mfma_f32_16x16x32_f16(af, bw[kc], acc, 0, 0, 0);
        }
        h4v pv;
        #pragma unroll
        for (int r = 0; r < 4; r++) pv[r] = (f16)acc[r];
        *(h4v*)&rep[w][l15 * 72 + ns * 16 + quad * 4] = pv;
    }
    #pragma unroll
    for (int j = 0; j < 2; j++){
        const h8v vv = *(const h8v*)&rep[w][(rrow + 8 * j) * 72 + rcol];
        *(h8v*)&gbuf[((size_t)(b * CB + w * 16 + rrow + 8 * j)) * NN + n0 + rcol] = vv;
    }
}

// ---------------------------------------------------------------------------
// Kernel 2: fused attention + final projection + residual.
// R13: 32 queries per wave (block = 128 queries, grid = 256). Shared phi/g
// tile reads amortized over 2x MFMA; defer-max softmax (skip rescale unless
// any query max grew by >8 in log2 domain; P bounded by 2^8, f16-safe).
// ---------------------------------------------------------------------------
union StageOrOut {
    struct { f16 ph[2][64 * 72]; f16 g[2][64 * 72]; } s;   // 36864 B (K-loop)
    float fO[128][68];                                      // 34816 B (epilogue)
};

__global__ __launch_bounds__(256, 1) void attn_kernel(
    const f16* __restrict__ thetaT, const f16* __restrict__ phiT,
    const f16* __restrict__ gbuf, const f16* __restrict__ wlp,
    const float* __restrict__ x, float* __restrict__ out)
{
    __shared__ __align__(16) StageOrOut sh;
    __shared__ __align__(16) f16 plds[4][32 * 72];  // per-wave P tile (32 q rows)

    const int b  = blockIdx.x & 7;                  // batch -> XCD swizzle
    const int q0 = (blockIdx.x >> 3) << 7;          // 128 queries per block
    const int t  = threadIdx.x;
    const int w = t >> 6, lane = t & 63, quad = lane >> 4, l15 = lane & 15;
    const int n0 = q0 + w * 32;

    // theta fragments for 32 queries (two 16-column groups)
    const size_t trow0 = ((size_t)(b * NN + n0 + l15)) * CB;
    const size_t trow1 = ((size_t)(b * NN + n0 + 16 + l15)) * CB;
    const h8v a0 = *(const h8v*)&thetaT[trow0 + quad * 8];
    const h8v a1 = *(const h8v*)&thetaT[trow0 + 32 + quad * 8];
    const h8v a2 = *(const h8v*)&thetaT[trow1 + quad * 8];
    const h8v a3 = *(const h8v*)&thetaT[trow1 + 32 + quad * 8];

    // staging: 256 threads stage the 64x64 phi tile and 64x64 g tile
    const int r0 = t >> 3, r1 = r0 + 32, c = (t & 7) * 8;
    const f16* pphi0 = phiT + ((size_t)(b * NN + r0)) * CB + c;
    const f16* pphi1 = phiT + ((size_t)(b * NN + r1)) * CB + c;
    const f16* pg0   = gbuf + ((size_t)(b * CB + r0)) * NN + c;
    const f16* pg1   = gbuf + ((size_t)(b * CB + r1)) * NN + c;
    const int lA = r0 * 72 + c, lB = r1 * 72 + c;

    h8v nA = *(const h8v*)pphi0;
    h8v nB = *(const h8v*)pphi1;
    h8v nC = *(const h8v*)pg0;
    h8v nD = *(const h8v*)pg1;
    *(h8v*)&sh.s.ph[0][lA] = nA;  *(h8v*)&sh.s.ph[0][lB] = nB;
    *(h8v*)&sh.s.g [0][lA] = nC;  *(h8v*)&sh.s.g [0][lB] = nD;

    float mrun0 = -1e30f, mrun1 = -1e30f, lrun0 = 0.f, lrun1 = 0.f;
    const f4v zf = {0.f, 0.f, 0.f, 0.f};
    f4v o[4][2];
    #pragma unroll
    for (int tt = 0; tt < 4; tt++){ o[tt][0] = zf; o[tt][1] = zf; }

    f16* const pw = &plds[w][0];

    for (int kb = 0; kb < 64; kb++){
        const int pb = kb & 1;
        __syncthreads();
        if (kb < 63){
            pphi0 += (size_t)64 * CB;  pphi1 += (size_t)64 * CB;
            pg0 += 64;                 pg1 += 64;
            nA = *(const h8v*)pphi0;   nB = *(const h8v*)pphi1;
            nC = *(const h8v*)pg0;     nD = *(const h8v*)pg1;
        }

        // ---- S^T = phi(A) * theta(B) for both query halves ----
        f4v s0[4], s1[4];
        #pragma unroll
        for (int tt = 0; tt < 4; tt++){
            const f16* pr = &sh.s.ph[pb][(tt * 16 + l15) * 72];
            const h8v pb0 = *(const h8v*)(pr + quad * 8);
            const h8v pb1 = *(const h8v*)(pr + 32 + quad * 8);
            f4v sv = zf;
            sv = __builtin_amdgcn_mfma_f32_16x16x32_f16(pb0, a0, sv, 0, 0, 0);
            sv = __builtin_amdgcn_mfma_f32_16x16x32_f16(pb1, a1, sv, 0, 0, 0);
            s0[tt] = sv;
            f4v sw = zf;
            sw = __builtin_amdgcn_mfma_f32_16x16x32_f16(pb0, a2, sw, 0, 0, 0);
            sw = __builtin_amdgcn_mfma_f32_16x16x32_f16(pb1, a3, sw, 0, 0, 0);
            s1[tt] = sw;
        }

        // ---- online softmax, defer-max (log2 domain; lane owns queries l15, 16+l15)
        float smax0 = fmaxf(fmaxf(s0[0][0], s0[0][1]), fmaxf(s0[0][2], s0[0][3]));
        float smax1 = fmaxf(fmaxf(s1[0][0], s1[0][1]), fmaxf(s1[0][2], s1[0][3]));
        #pragma unroll
        for (int tt = 1; tt < 4; tt++){
            smax0 = fmaxf(smax0, fmaxf(fmaxf(s0[tt][0], s0[tt][1]), fmaxf(s0[tt][2], s0[tt][3])));
            smax1 = fmaxf(smax1, fmaxf(fmaxf(s1[tt][0], s1[tt][1]), fmaxf(s1[tt][2], s1[tt][3])));
        }
        smax0 = fmaxf(smax0, __shfl_xor(smax0, 16));
        smax0 = fmaxf(smax0, __shfl_xor(smax0, 32));
        smax1 = fmaxf(smax1, __shfl_xor(smax1, 16));
        smax1 = fmaxf(smax1, __shfl_xor(smax1, 32));

        const float d = fmaxf(smax0 - mrun0, smax1 - mrun1);
        if (__any(d > 8.f)){
            const float mn0 = fmaxf(mrun0, smax0);
            const float mn1 = fmaxf(mrun1, smax1);
            const float al0 = __builtin_amdgcn_exp2f(mrun0 - mn0);
            const float al1 = __builtin_amdgcn_exp2f(mrun1 - mn1);
            mrun0 = mn0; mrun1 = mn1;
            lrun0 *= al0; lrun1 *= al1;
            #pragma unroll
            for (int tt = 0; tt < 4; tt++)
                #pragma unroll
                for (int r = 0; r < 4; r++){
                    o[tt][0][r] *= al0;
                    o[tt][1][r] *= al1;
                }
        }

        float ls0 = 0.f, ls1 = 0.f;
        #pragma unroll
        for (int tt = 0; tt < 4; tt++){
            h4v pv0, pv1;
            #pragma unroll
            for (int r = 0; r < 4; r++){
                float p = __builtin_amdgcn_exp2f(s0[tt][r] - mrun0);
                ls0 += p;  pv0[r] = (f16)p;
                float q = __builtin_amdgcn_exp2f(s1[tt][r] - mrun1);
                ls1 += q;  pv1[r] = (f16)q;
            }
            *(h4v*)&pw[l15 * 72 + tt * 16 + quad * 4]        = pv0;
            *(h4v*)&pw[(16 + l15) * 72 + tt * 16 + quad * 4] = pv1;
        }
        lrun0 += ls0;  lrun1 += ls1;

        const h8v paA = *(const h8v*)&pw[l15 * 72 + quad * 8];
        const h8v paB = *(const h8v*)&pw[l15 * 72 + 32 + quad * 8];
        const h8v paC = *(const h8v*)&pw[(16 + l15) * 72 + quad * 8];
        const h8v paD = *(const h8v*)&pw[(16 + l15) * 72 + 32 + quad * 8];

        // ---- O^T += g(A) * P^T(B), both query halves share g reads ----
        #pragma unroll
        for (int tt = 0; tt < 4; tt++){
            const f16* gr = &sh.s.g[pb][(tt * 16 + l15) * 72];
            const h8v gb0 = *(const h8v*)(gr + quad * 8);
            const h8v gb1 = *(const h8v*)(gr + 32 + quad * 8);
            o[tt][0] = __builtin_amdgcn_mfma_f32_16x16x32_f16(gb0, paA, o[tt][0], 0, 0, 0);
            o[tt][0] = __builtin_amdgcn_mfma_f32_16x16x32_f16(gb1, paB, o[tt][0], 0, 0, 0);
            o[tt][1] = __builtin_amdgcn_mfma_f32_16x16x32_f16(gb0, paC, o[tt][1], 0, 0, 0);
            o[tt][1] = __builtin_amdgcn_mfma_f32_16x16x32_f16(gb1, paD, o[tt][1], 0, 0, 0);
        }

        if (kb < 63){
            const int nb = pb ^ 1;
            *(h8v*)&sh.s.ph[nb][lA] = nA;  *(h8v*)&sh.s.ph[nb][lB] = nB;
            *(h8v*)&sh.s.g [nb][lA] = nC;  *(h8v*)&sh.s.g [nb][lB] = nD;
        }
    }

    lrun0 += __shfl_xor(lrun0, 16);
    lrun0 += __shfl_xor(lrun0, 32);
    lrun1 += __shfl_xor(lrun1, 16);
    lrun1 += __shfl_xor(lrun1, 32);
    const float inv0 = 1.0f / lrun0;
    const float inv1 = 1.0f / lrun1;

    #pragma unroll
    for (int tt = 0; tt < 4; tt++){
        h4v y0, y1;
        #pragma unroll
        for (int r = 0; r < 4; r++){
            y0[r] = (f16)(o[tt][0][r] * inv0);
            y1[r] = (f16)(o[tt][1][r] * inv1);
        }
        *(h4v*)&pw[l15 * 72 + tt * 16 + quad * 4]        = y0;
        *(h4v*)&pw[(16 + l15) * 72 + tt * 16 + quad * 4] = y1;
    }

    const h8v yB0 = *(const h8v*)&pw[l15 * 72 + quad * 8];
    const h8v yB1 = *(const h8v*)&pw[l15 * 72 + 32 + quad * 8];
    const h8v yB2 = *(const h8v*)&pw[(16 + l15) * 72 + quad * 8];
    const h8v yB3 = *(const h8v*)&pw[(16 + l15) * 72 + 32 + quad * 8];

    __syncthreads();   // staging region dead -> overlay fO

    // ---- out-GEMM + residual, two 64-column passes over fO[128][68] ----
    // pass 0: waves 0,1 (block-local queries 0..63)
    if (w < 2){
        #pragma unroll
        for (int cs = 0; cs < 8; cs++){
            const h8v wa0 = *(const h8v*)&wlp[(cs * 2 + 0) * 512 + lane * 8];
            const h8v wa1 = *(const h8v*)&wlp[(cs * 2 + 1) * 512 + lane * 8];
            f4v acc = zf;
            acc = __builtin_amdgcn_mfma_f32_16x16x32_f16(wa0, yB0, acc, 0, 0, 0);
            acc = __builtin_amdgcn_mfma_f32_16x16x32_f16(wa1, yB1, acc, 0, 0, 0);
            f4v acc1 = zf;
            acc1 = __builtin_amdgcn_mfma_f32_16x16x32_f16(wa0, yB2, acc1, 0, 0, 0);
            acc1 = __builtin_amdgcn_mfma_f32_16x16x32_f16(wa1, yB3, acc1, 0, 0, 0);
            #pragma unroll
            for (int r = 0; r < 4; r++){
                sh.fO[cs * 16 + quad * 4 + r][w * 32 + l15]      = acc[r];
                sh.fO[cs * 16 + quad * 4 + r][w * 32 + 16 + l15] = acc1[r];
            }
        }
    }
    __syncthreads();
    #pragma unroll
    for (int i = 0; i < 8; i++){
        const int row = i * 16 + (t >> 4);
        const int nf  = (t & 15) * 4;
        const f4v v = *(const f4v*)&sh.fO[row][nf];
        const size_t idx = ((size_t)(b * CC + row)) * NN + q0 + nf;
        const f4v xv = *(const f4v*)&x[idx];
        f4v ov;
        #pragma unroll
        for (int r = 0; r < 4; r++) ov[r] = v[r] + xv[r];
        *(f4v*)&out[idx] = ov;
    }
    __syncthreads();

    // pass 1: waves 2,3 (block-local queries 64..127)
    if (w >= 2){
        #pragma unroll
        for (int cs = 0; cs < 8; cs++){
            const h8v wa0 = *(const h8v*)&wlp[(cs * 2 + 0) * 512 + lane * 8];
            const h8v wa1 = *(const h8v*)&wlp[(cs * 2 + 1) * 512 + lane * 8];
            f4v acc = zf;
            acc = __builtin_amdgcn_mfma_f32_16x16x32_f16(wa0, yB0, acc, 0, 0, 0);
            acc = __builtin_amdgcn_mfma_f32_16x16x32_f16(wa1, yB1, acc, 0, 0, 0);
            f4v acc1 = zf;
            acc1 = __builtin_amdgcn_mfma_f32_16x16x32_f16(wa0, yB2, acc1, 0, 0, 0);
            acc1 = __builtin_amdgcn_mfma_f32_16x16x32_f16(wa1, yB3, acc1, 0, 0, 0);
            #pragma unroll
            for (int r = 0; r < 4; r++){
                sh.fO[cs * 16 + quad * 4 + r][(w - 2) * 32 + l15]      = acc[r];
                sh.fO[cs * 16 + quad * 4 + r][(w - 2) * 32 + 16 + l15] = acc1[r];
            }
        }
    }
    __syncthreads();
    #pragma unroll
    for (int i = 0; i < 8; i++){
        const int row = i * 16 + (t >> 4);
        const int nf  = (t & 15) * 4;
        const f4v v = *(const f4v*)&sh.fO[row][nf];
        const size_t idx = ((size_t)(b * CC + row)) * NN + q0 + 64 + nf;
        const f4v xv = *(const f4v*)&x[idx];
        f4v ov;
        #pragma unroll
        for (int r = 0; r < 4; r++) ov[r] = v[r] + xv[r];
        *(f4v*)&out[idx] = ov;
    }
}

extern "C" void kernel_launch(void* const* d_in, const int* in_sizes, int n_in,
                              void* d_out, int out_size, void* d_ws, size_t ws_size,
                              hipStream_t stream)
{
    const float* x   = (const float*)d_in[0];
    const float* wth = (const float*)d_in[1];
    const float* wph = (const float*)d_in[2];
    const float* wg  = (const float*)d_in[3];
    const float* wl  = (const float*)d_in[4];
    float* out = (float*)d_out;

    f16* thetaT = (f16*)d_ws;
    f16* phiT   = thetaT + (size_t)NB * NN * CB;
    f16* gbuf   = phiT   + (size_t)NB * NN * CB;
    f16* wthp   = gbuf   + (size_t)NB * NN * CB;
    f16* wphp   = wthp + 8192;
    f16* wgp    = wphp + 8192;
    f16* wlp    = wgp  + 8192;

    pack_w<<<8, 256, 0, stream>>>(wth, wph, wg, wl, wthp, wphp, wgp, wlp);
    proj_kernel<<<NB * 64, 256, 0, stream>>>(x, wthp, wphp, wgp, thetaT, phiT, gbuf);
    attn_kernel<<<NB * 32, 256, 0, stream>>>(thetaT, phiT, gbuf, wlp, x, out);
}